// Round 9
// baseline (175.844 us; speedup 1.0000x reference)
//
#include <hip/hip_runtime.h>

// AffinityFeature: out[b][a][h][w] = relu(cos(feat[b,:,h,w], feat[b,:,h+dh,w+dw])), 0 if OOB.
// a: 0:NW 1:N 2:NE 3:W 4:E 5:SW 6:S 7:SE. Symmetric: compute E,S,SE,SW per
// pixel, scatter mirrors (W,N,NW,NE) to the neighbor's location.
// R9: 1 px/thread -> 2048 blocks (8/CU = 32 waves/CU, FULL occupancy,
// __launch_bounds__(256,8) caps VGPR at 64). 4-channel load batches (20
// scalar loads) fenced with sched_barrier(0) so the compiler cannot sink
// them -> ~20 loads in flight/wave. All masking deferred to the epilogue.

#define AF_B 4
#define AF_C 32
#define AF_H 256
#define AF_W 512
#define AF_EPS 1e-12f
#define AF_PLANE ((size_t)AF_H * AF_W)
#define CB 4   // channels per fenced load batch

__global__ __launch_bounds__(256, 8) void affinity_occ_kernel(const float* __restrict__ f,
                                                              float* __restrict__ out) {
    // XCD-aware swizzle: 2048 blocks -> 256-block contiguous slab per XCD
    const int cpx = gridDim.x >> 3;
    const int bid = ((int)blockIdx.x & 7) * cpx + ((int)blockIdx.x >> 3);

    const int wband = bid & 1;                 // 2 half-rows of 256 px
    const int h = (bid >> 1) & (AF_H - 1);
    const int b = bid >> 9;
    const int w = (wband << 8) + (int)threadIdx.x;

    const bool vE = (w + 1) < AF_W;
    const bool vL = w > 0;
    const bool vS = (h + 1) < AF_H;
    const int offE = vE ? 1 : 0;     // clamped: OOB reads valid addr, result discarded
    const int offL = vL ? -1 : 0;

    const float* pc = f + (size_t)b * AF_C * AF_PLANE + (size_t)h * AF_W + w;
    const float* ps = pc + (vS ? AF_W : 0);

    float ssq = 0, esq = 0, s_sq = 0, se_sq = 0, sw_sq = 0;
    float dE = 0, dS = 0, dSE = 0, dSW = 0;

#pragma unroll
    for (int g = 0; g < AF_C / CB; ++g) {
        float vc[CB], ve[CB], vs_[CB], vse[CB], vsw[CB];
#pragma unroll
        for (int k = 0; k < CB; ++k) {
            const float* p = pc + (size_t)k * AF_PLANE;
            const float* q = ps + (size_t)k * AF_PLANE;
            vc[k]  = p[0];       // center (h, w)
            ve[k]  = p[offE];    // east   (h, w+1)
            vs_[k] = q[0];       // south  (h+1, w)
            vse[k] = q[offE];    // SE     (h+1, w+1)
            vsw[k] = q[offL];    // SW     (h+1, w-1)
        }
        __builtin_amdgcn_sched_barrier(0);   // keep the 20 loads clustered
#pragma unroll
        for (int k = 0; k < CB; ++k) {
            ssq   += vc[k]  * vc[k];
            esq   += ve[k]  * ve[k];
            s_sq  += vs_[k] * vs_[k];
            se_sq += vse[k] * vse[k];
            sw_sq += vsw[k] * vsw[k];
            dE    += vc[k]  * ve[k];
            dS    += vc[k]  * vs_[k];
            dSE   += vc[k]  * vse[k];
            dSW   += vc[k]  * vsw[k];
        }
        pc += (size_t)CB * AF_PLANE;
        ps += (size_t)CB * AF_PLANE;
    }

    const float ic  = 1.0f / fmaxf(sqrtf(ssq),   AF_EPS);
    const float ie  = 1.0f / fmaxf(sqrtf(esq),   AF_EPS);
    const float is_ = 1.0f / fmaxf(sqrtf(s_sq),  AF_EPS);
    const float ise = 1.0f / fmaxf(sqrtf(se_sq), AF_EPS);
    const float isw = 1.0f / fmaxf(sqrtf(sw_sq), AF_EPS);

    const float E  = vE         ? fmaxf(dE  * ic * ie,  0.0f) : 0.0f;
    const float S  = vS         ? fmaxf(dS  * ic * is_, 0.0f) : 0.0f;
    const float SE = (vS && vE) ? fmaxf(dSE * ic * ise, 0.0f) : 0.0f;
    const float SW = (vS && vL) ? fmaxf(dSW * ic * isw, 0.0f) : 0.0f;

    float* obase = out + (size_t)b * 8 * AF_PLANE + (size_t)h * AF_W + w;

    // forward channels at (h, w)
    obase[4 * AF_PLANE] = E;
    obase[5 * AF_PLANE] = SW;
    obase[6 * AF_PLANE] = S;
    obase[7 * AF_PLANE] = SE;

    // a=3 (W): W(h,w+1) = E(h,w)
    if (vE) obase[3 * AF_PLANE + 1] = E;
    if (!vL) obase[3 * AF_PLANE] = 0.0f;      // W(h,0) OOB

    if (vS) {
        float* on = obase + AF_W;             // row h+1, col w
        on[1 * AF_PLANE] = S;                 // N(h+1,w) = S(h,w)
        if (vE) on[0 * AF_PLANE + 1] = SE;    // NW(h+1,w+1) = SE(h,w)
        if (!vL) on[0 * AF_PLANE] = 0.0f;     // NW(h+1,0) OOB
        if (vL) on[2 * AF_PLANE - 1] = SW;    // NE(h+1,w-1) = SW(h,w)
        if (!vE) on[2 * AF_PLANE] = 0.0f;     // NE(h+1,W-1) OOB
    }

    if (h == 0) {                             // N/NW/NE at h=0 all OOB
        float* oz = out + (size_t)b * 8 * AF_PLANE + w;
        oz[0 * AF_PLANE] = 0.0f;
        oz[1 * AF_PLANE] = 0.0f;
        oz[2 * AF_PLANE] = 0.0f;
    }
}

extern "C" void kernel_launch(void* const* d_in, const int* in_sizes, int n_in,
                              void* d_out, int out_size, void* d_ws, size_t ws_size,
                              hipStream_t stream) {
    const float* f = (const float*)d_in[0];
    float* out = (float*)d_out;
    // 2048 blocks = 4 batches x 256 rows x 2 half-rows; 256 thr = 1 px each
    affinity_occ_kernel<<<2048, 256, 0, stream>>>(f, out);
}

// Round 10
// 26.568 us; speedup vs baseline: 6.6187x; 6.6187x over previous
//
#include <hip/hip_runtime.h>

// AffinityFeature: out[b][a][h][w] = relu(cos(feat[b,:,h,w], feat[b,:,h+dh,w+dw])), 0 if OOB.
// a: 0:NW 1:N 2:NE 3:W 4:E 5:SW 6:S 7:SE. Symmetric: compute E,S,SE,SW per
// pixel, scatter mirrors to the neighbor's location.
// R10: CHANNEL-SPLIT. Thread = 4 px x 8 channels; 4 channel-groups live in
// the same wave (lane = px | cg<<4), partial sums reduced with 2 shfl_xor
// steps. Serial chain per wave: 8 channel-iters (was 32). Grid 2048 blocks
// = 32 waves/CU fully resident. Vectorized loads/stores only (R9 lesson:
// scalar streams blow up L2 granularity 20x).

#define AF_B 4
#define AF_C 32
#define AF_H 256
#define AF_W 512
#define AF_EPS 1e-12f
#define AF_PLANE ((size_t)AF_H * AF_W)

__device__ __forceinline__ float redx(float v) {
    v += __shfl_xor(v, 16, 64);
    v += __shfl_xor(v, 32, 64);
    return v;
}

__global__ __launch_bounds__(256, 8) void affinity_split_kernel(const float* __restrict__ f,
                                                                float* __restrict__ out) {
    // XCD-aware swizzle: 2048 blocks -> 256-block contiguous slab per XCD
    const int cpx = gridDim.x >> 3;
    const int bid = ((int)blockIdx.x & 7) * cpx + ((int)blockIdx.x >> 3);
    const int whalf = bid & 1;                // which 256-px half row
    const int h = (bid >> 1) & (AF_H - 1);
    const int b = bid >> 9;

    const int tid = (int)threadIdx.x;
    const int lane = tid & 63;
    const int p = lane & 15;                  // px-group within wave
    const int cg = lane >> 4;                 // channel-group 0..3 (8 ch each)
    const int wv = tid >> 6;                  // wave in block
    const int w0 = (whalf << 8) + (((wv << 4) + p) << 2);   // 0..508 step 4

    const bool vR = (w0 + 4) < AF_W;
    const bool vL = w0 > 0;
    const bool vS = (h + 1) < AF_H;
    const float mS = vS ? 1.0f : 0.0f;
    const float mR = vR ? 1.0f : 0.0f;
    const float mRS = mR * mS;
    const float mLS = (vL ? 1.0f : 0.0f) * mS;
    const int offR = vR ? 4 : 0;
    const int offL = vL ? -1 : 0;

    const float* pc = f + ((size_t)b * AF_C + (size_t)(cg << 3)) * AF_PLANE
                        + (size_t)h * AF_W + w0;
    const float* ps = pc + (vS ? AF_W : 0);

    float ssq0=0,ssq1=0,ssq2=0,ssq3=0, ssqR=0;
    float nsq0=0,nsq1=0,nsq2=0,nsq3=0, nsqL=0,nsqR=0;
    float dE0=0,dE1=0,dE2=0,dE3=0;
    float dS0=0,dS1=0,dS2=0,dS3=0;
    float dSE0=0,dSE1=0,dSE2=0,dSE3=0;
    float dSW0=0,dSW1=0,dSW2=0,dSW3=0;

#pragma unroll
    for (int k = 0; k < 8; ++k) {           // this lane's 8 channels
        const float4 cc = *(const float4*)pc;
        const float ccR = pc[offR] * mR;
        float4 cs = *(const float4*)ps;
        const float csR = ps[offR] * mRS;
        const float csL = ps[offL] * mLS;
        cs.x *= mS; cs.y *= mS; cs.z *= mS; cs.w *= mS;
        pc += AF_PLANE; ps += AF_PLANE;

        ssq0 += cc.x*cc.x; ssq1 += cc.y*cc.y; ssq2 += cc.z*cc.z; ssq3 += cc.w*cc.w;
        ssqR += ccR*ccR;
        nsq0 += cs.x*cs.x; nsq1 += cs.y*cs.y; nsq2 += cs.z*cs.z; nsq3 += cs.w*cs.w;
        nsqL += csL*csL;   nsqR += csR*csR;
        dE0 += cc.x*cc.y;  dE1 += cc.y*cc.z;  dE2 += cc.z*cc.w;  dE3 += cc.w*ccR;
        dS0 += cc.x*cs.x;  dS1 += cc.y*cs.y;  dS2 += cc.z*cs.z;  dS3 += cc.w*cs.w;
        dSE0 += cc.x*cs.y; dSE1 += cc.y*cs.z; dSE2 += cc.z*cs.w; dSE3 += cc.w*csR;
        dSW0 += cc.x*csL;  dSW1 += cc.y*cs.x; dSW2 += cc.z*cs.y; dSW3 += cc.w*cs.z;
    }

    // ---- reduce the 4 channel-group partials within the wave ----
    ssq0=redx(ssq0); ssq1=redx(ssq1); ssq2=redx(ssq2); ssq3=redx(ssq3); ssqR=redx(ssqR);
    nsq0=redx(nsq0); nsq1=redx(nsq1); nsq2=redx(nsq2); nsq3=redx(nsq3);
    nsqL=redx(nsqL); nsqR=redx(nsqR);
    dE0=redx(dE0);   dE1=redx(dE1);   dE2=redx(dE2);   dE3=redx(dE3);
    dS0=redx(dS0);   dS1=redx(dS1);   dS2=redx(dS2);   dS3=redx(dS3);
    dSE0=redx(dSE0); dSE1=redx(dSE1); dSE2=redx(dSE2); dSE3=redx(dSE3);
    dSW0=redx(dSW0); dSW1=redx(dSW1); dSW2=redx(dSW2); dSW3=redx(dSW3);

    const float ic0 = 1.0f / fmaxf(sqrtf(ssq0), AF_EPS);
    const float ic1 = 1.0f / fmaxf(sqrtf(ssq1), AF_EPS);
    const float ic2 = 1.0f / fmaxf(sqrtf(ssq2), AF_EPS);
    const float ic3 = 1.0f / fmaxf(sqrtf(ssq3), AF_EPS);
    const float icR = 1.0f / fmaxf(sqrtf(ssqR), AF_EPS);
    const float is0 = 1.0f / fmaxf(sqrtf(nsq0), AF_EPS);
    const float is1 = 1.0f / fmaxf(sqrtf(nsq1), AF_EPS);
    const float is2 = 1.0f / fmaxf(sqrtf(nsq2), AF_EPS);
    const float is3 = 1.0f / fmaxf(sqrtf(nsq3), AF_EPS);
    const float isL = 1.0f / fmaxf(sqrtf(nsqL), AF_EPS);
    const float isR = 1.0f / fmaxf(sqrtf(nsqR), AF_EPS);

    const float E0 = fmaxf(dE0*ic0*ic1, 0.0f);
    const float E1 = fmaxf(dE1*ic1*ic2, 0.0f);
    const float E2 = fmaxf(dE2*ic2*ic3, 0.0f);
    const float E3 = fmaxf(dE3*ic3*icR, 0.0f);
    const float S0 = fmaxf(dS0*ic0*is0, 0.0f);
    const float S1 = fmaxf(dS1*ic1*is1, 0.0f);
    const float S2 = fmaxf(dS2*ic2*is2, 0.0f);
    const float S3 = fmaxf(dS3*ic3*is3, 0.0f);
    const float SE0 = fmaxf(dSE0*ic0*is1, 0.0f);
    const float SE1 = fmaxf(dSE1*ic1*is2, 0.0f);
    const float SE2 = fmaxf(dSE2*ic2*is3, 0.0f);
    const float SE3 = fmaxf(dSE3*ic3*isR, 0.0f);
    const float SW0 = fmaxf(dSW0*ic0*isL, 0.0f);
    const float SW1 = fmaxf(dSW1*ic1*is0, 0.0f);
    const float SW2 = fmaxf(dSW2*ic2*is1, 0.0f);
    const float SW3 = fmaxf(dSW3*ic3*is2, 0.0f);

    // ---- stores split by channel-group (all lanes hold full results) ----
    float* ob = out + (size_t)b * 8 * AF_PLANE + (size_t)h * AF_W + w0;
    float* oz = out + (size_t)b * 8 * AF_PLANE + w0;   // row 0
    const float4 z4 = make_float4(0.f, 0.f, 0.f, 0.f);

    if (cg == 0) {
        *(float4*)(ob + 4*AF_PLANE) = make_float4(E0, E1, E2, E3);
        float* o3 = ob + 3*AF_PLANE;          // W(h,w) = E(h,w-1)
        o3[1] = E0; o3[2] = E1; o3[3] = E2;
        if (vR) o3[4] = E3;
        if (!vL) o3[0] = 0.0f;
        if (h == 0) *(float4*)(oz + 0*AF_PLANE) = z4;
    } else if (cg == 1) {
        *(float4*)(ob + 5*AF_PLANE) = make_float4(SW0, SW1, SW2, SW3);
        if (vS) {
            float* o2 = ob + AF_W + 2*AF_PLANE;   // NE(h+1,w) = SW(h,w+1)
            if (vL) o2[-1] = SW0;
            o2[0] = SW1; o2[1] = SW2; o2[2] = SW3;
            if (!vR) o2[3] = 0.0f;
        }
        if (h == 0) *(float4*)(oz + 1*AF_PLANE) = z4;
    } else if (cg == 2) {
        *(float4*)(ob + 6*AF_PLANE) = make_float4(S0, S1, S2, S3);
        if (vS)                                  // N(h+1,w) = S(h,w)
            *(float4*)(ob + AF_W + 1*AF_PLANE) = make_float4(S0, S1, S2, S3);
        if (h == 0) *(float4*)(oz + 2*AF_PLANE) = z4;
    } else {
        *(float4*)(ob + 7*AF_PLANE) = make_float4(SE0, SE1, SE2, SE3);
        if (vS) {
            float* o0 = ob + AF_W;               // NW(h+1,w) = SE(h,w-1)
            o0[1] = SE0; o0[2] = SE1; o0[3] = SE2;
            if (vR) o0[4] = SE3;
            if (!vL) o0[0] = 0.0f;
        }
    }
}

extern "C" void kernel_launch(void* const* d_in, const int* in_sizes, int n_in,
                              void* d_out, int out_size, void* d_ws, size_t ws_size,
                              hipStream_t stream) {
    const float* f = (const float*)d_in[0];
    float* out = (float*)d_out;
    // 2048 blocks = 4 b x 256 h x 2 half-rows; thread = 4 px x 8 ch
    affinity_split_kernel<<<2048, 256, 0, stream>>>(f, out);
}